// Round 1
// baseline (147.602 us; speedup 1.0000x reference)
//
#include <hip/hip_runtime.h>

// SegmentMM: out[i] = A[i] (1x64) @ B_eff[segA[i]] (64x64), N=131072, K=M=64, S=128.
// segment_id_A sorted; B_eff[segB[j]] = B[j] (identity permutation in practice).
//
// Strategy: memory-bound fp32 vector kernel.
//  - lane l of a wave owns output column l; B[seg] column l lives in 64 VGPRs.
//  - A row values are wave-uniform -> readfirstlane forces scalar (s_load) path.
//  - sorted segments => B register reload ~once per wave.

#define ROWS_PER_WAVE 32

__global__ void build_inv_kernel(const int* __restrict__ segB, int* __restrict__ inv, int S) {
    int j = threadIdx.x + blockIdx.x * blockDim.x;
    if (j < S) inv[segB[j]] = j;
}

__global__ __launch_bounds__(256, 4) void segmm_kernel(
        const float* __restrict__ A,     // [N,64]
        const float* __restrict__ B,     // [S,64,64]
        const int*   __restrict__ segA,  // [N]
        const int*   __restrict__ inv,   // [S] inverse of segment_id_B
        float*       __restrict__ out,   // [N,64]
        int nrows) {
    const int lane        = threadIdx.x & 63;
    const int waveInBlock = threadIdx.x >> 6;

    int r0 = (blockIdx.x * 4 + waveInBlock) * ROWS_PER_WAVE;
    // Force wave-uniformity so segA[r] / A[r*64+k] compile to scalar loads.
    r0 = __builtin_amdgcn_readfirstlane(r0);
    if (r0 >= nrows) return;

    float b[64];            // column `lane` of B[current segment]
    int s_cur = -1;

    const int rEnd = (r0 + ROWS_PER_WAVE < nrows) ? (r0 + ROWS_PER_WAVE) : nrows;
    for (int r = r0; r < rEnd; ++r) {
        int s = __builtin_amdgcn_readfirstlane(segA[r]);
        if (s != s_cur) {
            s_cur = s;
            int j = inv[s];  // uniform -> scalar load
            const float* __restrict__ bp = B + (size_t)j * 4096 + lane;
            #pragma unroll
            for (int k = 0; k < 64; ++k) b[k] = bp[(size_t)k * 64];  // coalesced
        }
        const float* __restrict__ ap = A + (size_t)r * 64;  // uniform base
        float acc0 = 0.f, acc1 = 0.f, acc2 = 0.f, acc3 = 0.f;
        #pragma unroll
        for (int k = 0; k < 64; k += 4) {
            acc0 = fmaf(ap[k + 0], b[k + 0], acc0);
            acc1 = fmaf(ap[k + 1], b[k + 1], acc1);
            acc2 = fmaf(ap[k + 2], b[k + 2], acc2);
            acc3 = fmaf(ap[k + 3], b[k + 3], acc3);
        }
        out[(size_t)r * 64 + lane] = (acc0 + acc1) + (acc2 + acc3);
    }
}

extern "C" void kernel_launch(void* const* d_in, const int* in_sizes, int n_in,
                              void* d_out, int out_size, void* d_ws, size_t ws_size,
                              hipStream_t stream) {
    const float* A    = (const float*)d_in[0];
    const float* B    = (const float*)d_in[1];
    const int*   segA = (const int*)d_in[2];
    const int*   segB = (const int*)d_in[3];
    float*       out  = (float*)d_out;
    int*         inv  = (int*)d_ws;   // S ints of scratch

    const int K = 64;
    const int N = in_sizes[0] / K;    // 131072
    const int S = in_sizes[3];        // 128

    build_inv_kernel<<<(S + 127) / 128, 128, 0, stream>>>(segB, inv, S);

    int waves  = (N + ROWS_PER_WAVE - 1) / ROWS_PER_WAVE;
    int blocks = (waves + 3) / 4;     // 4 waves (256 threads) per block
    segmm_kernel<<<blocks, 256, 0, stream>>>(A, B, segA, inv, out, N);
}

// Round 2
// 136.987 us; speedup vs baseline: 1.0775x; 1.0775x over previous
//
#include <hip/hip_runtime.h>

// SegmentMM: out[i] = A[i] (1x64) @ B_eff[segA[i]] (64x64), N=131072, K=M=64, S=128.
// segment_id_A sorted; B_eff[segB[j]] = B[j].
//
// lane l of a wave owns output column l; B[seg] column l lives in 64 VGPRs
// held as 4x f32x16 ext-vectors (constant-indexed only -> stays in registers;
// a plain float[64] was demoted to scratch in round 1: VGPR_Count=36).
// A-row loads are wave-uniform (readfirstlane'd base) -> scalar loads.
// sorted segments => B register reload ~once per wave.

typedef float f32x16 __attribute__((ext_vector_type(16)));

#define RPW 32  // rows per wave

__global__ void build_inv_kernel(const int* __restrict__ segB, int* __restrict__ inv, int S) {
    int j = threadIdx.x + blockIdx.x * blockDim.x;
    if (j < S) inv[segB[j]] = j;
}

__global__ __launch_bounds__(256, 4) void segmm_kernel(
        const float* __restrict__ A,     // [N,64]
        const float* __restrict__ B,     // [S,64,64]
        const int*   __restrict__ segA,  // [N]
        const int*   __restrict__ inv,   // [S] inverse of segment_id_B
        float*       __restrict__ out,   // [N,64]
        int nrows) {
    const int lane = threadIdx.x & 63;

    int r0 = ((blockIdx.x << 2) + (threadIdx.x >> 6)) * RPW;
    r0 = __builtin_amdgcn_readfirstlane(r0);   // wave-uniform row base
    if (r0 >= nrows) return;
    const int rEnd = (r0 + RPW < nrows) ? (r0 + RPW) : nrows;

    f32x16 b0 = 0.f, b1 = 0.f, b2 = 0.f, b3 = 0.f;  // column `lane` of B[seg]
    int s_cur = -1;

    for (int r = r0; r < rEnd; ++r) {
        int s = __builtin_amdgcn_readfirstlane(segA[r]);
        if (s != s_cur) {
            s_cur = s;
            int j = inv[s];  // uniform -> scalar load
            const float* __restrict__ bp = B + (size_t)j * 4096 + lane;
            #pragma unroll
            for (int i = 0; i < 16; ++i) b0[i] = bp[(size_t)(i      ) * 64];
            #pragma unroll
            for (int i = 0; i < 16; ++i) b1[i] = bp[(size_t)(i + 16) * 64];
            #pragma unroll
            for (int i = 0; i < 16; ++i) b2[i] = bp[(size_t)(i + 32) * 64];
            #pragma unroll
            for (int i = 0; i < 16; ++i) b3[i] = bp[(size_t)(i + 48) * 64];
        }
        const float* __restrict__ ap = A + (size_t)r * 64;  // uniform base
        float acc0 = 0.f, acc1 = 0.f, acc2 = 0.f, acc3 = 0.f;
        #pragma unroll
        for (int i = 0; i < 16; ++i) {
            acc0 = fmaf(ap[i     ], b0[i], acc0);
            acc1 = fmaf(ap[i + 16], b1[i], acc1);
            acc2 = fmaf(ap[i + 32], b2[i], acc2);
            acc3 = fmaf(ap[i + 48], b3[i], acc3);
        }
        out[(size_t)r * 64 + lane] = (acc0 + acc1) + (acc2 + acc3);
    }
}

extern "C" void kernel_launch(void* const* d_in, const int* in_sizes, int n_in,
                              void* d_out, int out_size, void* d_ws, size_t ws_size,
                              hipStream_t stream) {
    const float* A    = (const float*)d_in[0];
    const float* B    = (const float*)d_in[1];
    const int*   segA = (const int*)d_in[2];
    const int*   segB = (const int*)d_in[3];
    float*       out  = (float*)d_out;
    int*         inv  = (int*)d_ws;   // S ints of scratch

    const int K = 64;
    const int N = in_sizes[0] / K;    // 131072
    const int S = in_sizes[3];        // 128

    build_inv_kernel<<<(S + 127) / 128, 128, 0, stream>>>(segB, inv, S);

    int waves  = (N + RPW - 1) / RPW;
    int blocks = (waves + 3) / 4;     // 4 waves (256 threads) per block
    segmm_kernel<<<blocks, 256, 0, stream>>>(A, B, segA, inv, out, N);
}

// Round 5
// 107.641 us; speedup vs baseline: 1.3712x; 1.2726x over previous
//
#include <hip/hip_runtime.h>

// SegmentMM: out[i] = A[i] (1x64) @ B_eff[segA[i]] (64x64), N=131072, K=M=64, S=128.
// segment_id_A sorted; B_eff[segB[j]] = B[j].
//
// Round-3 strategy: bf16 MFMA (threshold 0.98 >> bf16 error ~0.3).
//  - Wave owns 32 rows = two 16-row tiles. Per tile: 8x mfma_f32_16x16x32_bf16.
//  - B[seg] lives in 8 pinned fragments (32 VGPRs); asm "+v" pin defeats the
//    scheduler's load-rematerialization (rounds 1-2: VGPR_Count=40, B re-read
//    per row from cache -> latency-bound 90us).
//  - Boundary tiles (segment changes mid-tile, ~127/8192) use per-row fp32.
// Fragment maps (16x16x32): A: row=lane&15, k=(lane>>4)*8+i (+32*kstep)
//                           B: col=lane&15, k=(lane>>4)*8+i (+32*kstep)
//                           D: col=lane&15, row=(lane>>4)*4+reg   [m89-verified]

typedef float f32x4 __attribute__((ext_vector_type(4)));
typedef short s16x8 __attribute__((ext_vector_type(8)));

#define WPB 4    // waves per block
#define RPW 32   // rows per wave (2 MFMA tiles)

__global__ void build_inv_kernel(const int* __restrict__ segB, int* __restrict__ inv, int S) {
    int j = threadIdx.x + blockIdx.x * blockDim.x;
    if (j < S) inv[segB[j]] = j;
}

__device__ __forceinline__ short f2bf(float f) {  // RNE f32 -> bf16 bits
    unsigned u = __builtin_bit_cast(unsigned, f);
    u += 0x7fffu + ((u >> 16) & 1u);
    return (short)(u >> 16);
}

__global__ __launch_bounds__(256, 4) void segmm_mfma(
        const float* __restrict__ A,     // [N,64]
        const float* __restrict__ B,     // [S,64,64]
        const int*   __restrict__ segA,  // [N] sorted
        const int*   __restrict__ inv,   // [S] inverse of segment_id_B
        float*       __restrict__ out,   // [N,64]
        int nrows) {
    const int lane  = threadIdx.x & 63;
    const int row16 = lane & 15;   // A row within tile / B,D col within 16
    const int kgrp  = lane >> 4;   // 0..3

    int w  = blockIdx.x * WPB + (threadIdx.x >> 6);
    int r0 = __builtin_amdgcn_readfirstlane(w * RPW);
    if (r0 >= nrows) return;

    s16x8 bf00, bf01, bf10, bf11, bf20, bf21, bf30, bf31;  // [ct][kstep]
    int j_cur = -1;

    #pragma unroll
    for (int t = 0; t < RPW / 16; ++t) {
        const int rt = r0 + 16 * t;
        const int s0 = __builtin_amdgcn_readfirstlane(segA[rt]);
        const int s1 = __builtin_amdgcn_readfirstlane(segA[rt + 15]);

        if (s0 == s1) {
            const int j = __builtin_amdgcn_readfirstlane(inv[s0]);
            if (j != j_cur) {
                j_cur = j;
                const float* __restrict__ bp = B + (size_t)j * 4096;
                const int col = row16;  // frag col base; ct adds 16*ct
                #define LOADB(frag, ct, ks) do {                                  \
                    s16x8 f;                                                      \
                    const float* q = bp + (size_t)(kgrp * 8 + (ks) * 32) * 64     \
                                        + (ct) * 16 + col;                        \
                    _Pragma("unroll")                                             \
                    for (int i = 0; i < 8; ++i) f[i] = f2bf(q[(size_t)i * 64]);   \
                    frag = f; } while (0)
                LOADB(bf00, 0, 0); LOADB(bf01, 0, 1);
                LOADB(bf10, 1, 0); LOADB(bf11, 1, 1);
                LOADB(bf20, 2, 0); LOADB(bf21, 2, 1);
                LOADB(bf30, 3, 0); LOADB(bf31, 3, 1);
                #undef LOADB
                // Pin: forbid load rematerialization / sinking of B fragments.
                asm volatile("" : "+v"(bf00), "+v"(bf01), "+v"(bf10), "+v"(bf11),
                                  "+v"(bf20), "+v"(bf21), "+v"(bf30), "+v"(bf31));
            }

            // A fragments for this tile (fp32 load + cvt)
            s16x8 af0, af1;
            {
                const float* __restrict__ ap =
                    A + (size_t)(rt + row16) * 64 + kgrp * 8;
                f32x4 lo = *(const f32x4*)(ap);
                f32x4 hi = *(const f32x4*)(ap + 4);
                af0[0]=f2bf(lo[0]); af0[1]=f2bf(lo[1]); af0[2]=f2bf(lo[2]); af0[3]=f2bf(lo[3]);
                af0[4]=f2bf(hi[0]); af0[5]=f2bf(hi[1]); af0[6]=f2bf(hi[2]); af0[7]=f2bf(hi[3]);
                f32x4 lo2 = *(const f32x4*)(ap + 32);
                f32x4 hi2 = *(const f32x4*)(ap + 36);
                af1[0]=f2bf(lo2[0]); af1[1]=f2bf(lo2[1]); af1[2]=f2bf(lo2[2]); af1[3]=f2bf(lo2[3]);
                af1[4]=f2bf(hi2[0]); af1[5]=f2bf(hi2[1]); af1[6]=f2bf(hi2[2]); af1[7]=f2bf(hi2[3]);
            }

            #define DOTILE(b0, b1, ct) do {                                       \
                f32x4 acc = {0.f, 0.f, 0.f, 0.f};                                 \
                acc = __builtin_amdgcn_mfma_f32_16x16x32_bf16(af0, b0, acc, 0,0,0);\
                acc = __builtin_amdgcn_mfma_f32_16x16x32_bf16(af1, b1, acc, 0,0,0);\
                _Pragma("unroll")                                                 \
                for (int reg = 0; reg < 4; ++reg)                                 \
                    out[(size_t)(rt + kgrp * 4 + reg) * 64 + (ct) * 16 + row16]   \
                        = acc[reg];                                               \
            } while (0)
            DOTILE(bf00, bf01, 0);
            DOTILE(bf10, bf11, 1);
            DOTILE(bf20, bf21, 2);
            DOTILE(bf30, bf31, 3);
            #undef DOTILE
        } else {
            // segment boundary inside tile: per-row fp32 path (rare)
            for (int r = rt; r < rt + 16; ++r) {
                const int s = __builtin_amdgcn_readfirstlane(segA[r]);
                const int j = __builtin_amdgcn_readfirstlane(inv[s]);
                const float* __restrict__ ap = A + (size_t)r * 64;
                const float* __restrict__ bp = B + (size_t)j * 4096 + lane;
                float a0 = 0.f, a1 = 0.f, a2 = 0.f, a3 = 0.f;
                #pragma unroll
                for (int k = 0; k < 64; k += 4) {
                    a0 = fmaf(ap[k + 0], bp[(size_t)(k + 0) * 64], a0);
                    a1 = fmaf(ap[k + 1], bp[(size_t)(k + 1) * 64], a1);
                    a2 = fmaf(ap[k + 2], bp[(size_t)(k + 2) * 64], a2);
                    a3 = fmaf(ap[k + 3], bp[(size_t)(k + 3) * 64], a3);
                }
                out[(size_t)r * 64 + lane] = (a0 + a1) + (a2 + a3);
            }
        }
    }
}

extern "C" void kernel_launch(void* const* d_in, const int* in_sizes, int n_in,
                              void* d_out, int out_size, void* d_ws, size_t ws_size,
                              hipStream_t stream) {
    const float* A    = (const float*)d_in[0];
    const float* B    = (const float*)d_in[1];
    const int*   segA = (const int*)d_in[2];
    const int*   segB = (const int*)d_in[3];
    float*       out  = (float*)d_out;
    int*         inv  = (int*)d_ws;   // S ints of scratch

    const int K = 64;
    const int N = in_sizes[0] / K;    // 131072
    const int S = in_sizes[3];        // 128

    build_inv_kernel<<<(S + 127) / 128, 128, 0, stream>>>(segB, inv, S);

    int waves  = (N + RPW - 1) / RPW;          // 4096
    int blocks = (waves + WPB - 1) / WPB;      // 1024
    segmm_mfma<<<blocks, 256, 0, stream>>>(A, B, segA, inv, out, N);
}